// Round 9
// baseline (137.701 us; speedup 1.0000x reference)
//
#include <hip/hip_runtime.h>
#include <hip/hip_bf16.h>
#include <cstdint>

#define T_TOK 1024
#define H_DIM 1024
#define F_DIM 2048
#define NE 8
#define BK 32
#define LDT 40  // padded LDS row stride in bf16 elements (80 B; banks spread, <=2-way)
#define NKU (H_DIM / BK)   // 32
#define KSPLIT 2
#define KCH (F_DIM / KSPLIT)  // 1024 per down block
#define NKD (KCH / BK)     // 32

typedef __attribute__((ext_vector_type(8))) __bf16 bf16x8;
typedef __attribute__((ext_vector_type(4))) float f32x4;

__device__ __forceinline__ ushort f2b(float f) {
    union { float f; uint32_t u; } v; v.f = f;
    uint32_t r = v.u + 0x7FFFu + ((v.u >> 16) & 1u);  // RNE
    return (ushort)(r >> 16);
}
// packed f32x2 -> bf16x2 via compiler pattern (emits v_cvt_pk_bf16_f32)
__device__ __forceinline__ uint32_t pkcvt(float a, float b) {
    __hip_bfloat162 h = __float22bfloat162_rn(float2{a, b});
    union { __hip_bfloat162 h; uint32_t u; } c; c.h = h; return c.u;
}

// ---------------- router: logits (fp32, exact output), top-2, bucket, x->bf16 ----------------
__global__ __launch_bounds__(64) void router_kernel(
    const float* __restrict__ x, const float* __restrict__ gw,
    float* __restrict__ logits_out, ushort* __restrict__ xb,
    int* __restrict__ cnt, int* __restrict__ tlist, float* __restrict__ wlist)
{
    const int t = blockIdx.x;
    const int l = threadIdx.x;
    const float* xr = x + (size_t)t * H_DIM;
    float4 xv[4];
#pragma unroll
    for (int j = 0; j < 4; ++j) xv[j] = ((const float4*)xr)[l * 4 + j];

    {   // bf16 copy of x row (lane covers 16 contiguous elements)
        uint4 p0, p1;
        p0.x = pkcvt(xv[0].x, xv[0].y);
        p0.y = pkcvt(xv[0].z, xv[0].w);
        p0.z = pkcvt(xv[1].x, xv[1].y);
        p0.w = pkcvt(xv[1].z, xv[1].w);
        p1.x = pkcvt(xv[2].x, xv[2].y);
        p1.y = pkcvt(xv[2].z, xv[2].w);
        p1.z = pkcvt(xv[3].x, xv[3].y);
        p1.w = pkcvt(xv[3].z, xv[3].w);
        uint4* dst = (uint4*)(xb + (size_t)t * H_DIM + l * 16);
        dst[0] = p0; dst[1] = p1;
    }

    float lg[NE];
#pragma unroll
    for (int e = 0; e < NE; ++e) {
        const float* g = gw + (size_t)e * H_DIM;
        float s = 0.f;
#pragma unroll
        for (int j = 0; j < 4; ++j) {
            float4 gv = ((const float4*)g)[l * 4 + j];
            s += xv[j].x * gv.x + xv[j].y * gv.y + xv[j].z * gv.z + xv[j].w * gv.w;
        }
#pragma unroll
        for (int off = 32; off > 0; off >>= 1) s += __shfl_xor(s, off);
        lg[e] = s;
    }
    if (l < NE) logits_out[t * NE + l] = lg[l];

    if (l == 0) {
        int e0 = 0; float m0 = lg[0];
        for (int e = 1; e < NE; ++e) if (lg[e] > m0) { m0 = lg[e]; e0 = e; }
        int e1 = (e0 == 0) ? 1 : 0; float m1 = lg[e1];
        for (int e = 0; e < NE; ++e) if (e != e0 && lg[e] > m1) { m1 = lg[e]; e1 = e; }
        float p1 = __expf(m1 - m0);
        float w0 = 1.f / (1.f + p1);
        float w1v = p1 * w0;
        int p = atomicAdd(&cnt[e0], 1);
        tlist[e0 * T_TOK + p] = t; wlist[e0 * T_TOK + p] = w0;
        p = atomicAdd(&cnt[e1], 1);
        tlist[e1 * T_TOK + p] = t; wlist[e1 * T_TOK + p] = w1v;
    }
}

// ---------------- prefix: 128-aligned packed offsets for act ----------------
__global__ void prefix_kernel(const int* __restrict__ cnt, int* __restrict__ aofs) {
    if (threadIdx.x == 0 && blockIdx.x == 0) {
        int o = 0;
        for (int e = 0; e < NE; ++e) { aofs[e] = o; o += ((cnt[e] + 127) >> 7) << 7; }
    }
}

// packed-convert write macro (plain named locals only — rule #20)
#define PKW(d, s0, s1) { d.x = pkcvt(s0.x, s0.y); d.y = pkcvt(s0.z, s0.w); \
                         d.z = pkcvt(s1.x, s1.y); d.w = pkcvt(s1.z, s1.w); }

// ---------------- up: act = silu(X W1^T) * (X W3^T) * route_w ----------------
// tile: 128 tokens x 64 F-cols, BK=32, 2-deep reg pipeline over 2 LDS buffers.
// sched_barrier(0) pins load-issue early; (256,2) gives the allocator room to
// keep staging live across MFMA (r8: worked, up 88 -> ~47 us).
__global__ __launch_bounds__(256, 2) void up_kernel(
    const float* __restrict__ w1, const float* __restrict__ w3,
    const ushort* __restrict__ xb,
    const int* __restrict__ cnt, const int* __restrict__ aofs,
    const int* __restrict__ tlist, const float* __restrict__ wlist,
    ushort* __restrict__ act)
{
    const int e = blockIdx.z, tt = blockIdx.y, ft = blockIdx.x;  // ft 0..31
    const int n = cnt[e];
    if (tt * 128 >= n) return;

    __shared__ int tok[128];
    __shared__ float wt[128];
    __shared__ __align__(16) ushort lds_a[2][128 * LDT];
    __shared__ __align__(16) ushort lds_b1[2][64 * LDT];
    __shared__ __align__(16) ushort lds_b3[2][64 * LDT];

    const int tid = threadIdx.x;
    if (tid < 128) {
        int slot = tt * 128 + tid;
        bool v = slot < n;
        tok[tid] = v ? tlist[e * T_TOK + slot] : 0;
        wt[tid]  = v ? wlist[e * T_TOK + slot] : 0.f;
    }
    __syncthreads();

    const int arow = tid >> 1, aseg = tid & 1;   // A: 128 rows x 2 segs, 32B/thread
    const int brow = tid >> 2, bpart = tid & 3;  // B: 64 rows x 4 segs, 8 fp32/thread
    const ushort* asrc = xb + (size_t)tok[arow] * H_DIM + aseg * 16;
    const float* b1src = w1 + ((size_t)e * F_DIM + (size_t)ft * 64 + brow) * H_DIM + bpart * 8;
    const float* b3src = w3 + ((size_t)e * F_DIM + (size_t)ft * 64 + brow) * H_DIM + bpart * 8;

    uint4 arA0, arA1, arB0, arB1;
    float4 b1A0, b1A1, b1B0, b1B1;
    float4 b3A0, b3A1, b3B0, b3B1;

#define LOADU(S, k0) { const uint4* s_ = (const uint4*)(asrc + (k0)); \
        ar##S##0 = s_[0]; ar##S##1 = s_[1]; \
        const float4* p1_ = (const float4*)(b1src + (k0)); \
        b1##S##0 = p1_[0]; b1##S##1 = p1_[1]; \
        const float4* p3_ = (const float4*)(b3src + (k0)); \
        b3##S##0 = p3_[0]; b3##S##1 = p3_[1]; }

#define WRITEU(S, buf) { uint4* da_ = (uint4*)&lds_a[buf][arow * LDT + aseg * 16]; \
        da_[0] = ar##S##0; da_[1] = ar##S##1; \
        uint4 pk_; PKW(pk_, b1##S##0, b1##S##1); \
        *(uint4*)&lds_b1[buf][brow * LDT + bpart * 8] = pk_; \
        PKW(pk_, b3##S##0, b3##S##1); \
        *(uint4*)&lds_b3[buf][brow * LDT + bpart * 8] = pk_; }

    const int l = tid & 63, w = tid >> 6;
    const int wm = w >> 1, wn = w & 1;           // wave tile: 64 rows x 32 cols
    const int lr = l & 15, kg = l >> 4;

    f32x4 acc1[4][2], acc3[4][2];
#pragma unroll
    for (int m = 0; m < 4; ++m)
#pragma unroll
        for (int nn = 0; nn < 2; ++nn) {
            acc1[m][nn] = (f32x4){0.f, 0.f, 0.f, 0.f};
            acc3[m][nn] = (f32x4){0.f, 0.f, 0.f, 0.f};
        }

    auto mfma_step = [&](int buf) {
        const ushort* la  = lds_a[buf];
        const ushort* lb1 = lds_b1[buf];
        const ushort* lb3 = lds_b3[buf];
        bf16x8 a[4];
#pragma unroll
        for (int m = 0; m < 4; ++m)
            a[m] = *(const bf16x8*)&la[(wm * 64 + m * 16 + lr) * LDT + kg * 8];
#pragma unroll
        for (int nn = 0; nn < 2; ++nn) {
            bf16x8 b1 = *(const bf16x8*)&lb1[(wn * 32 + nn * 16 + lr) * LDT + kg * 8];
            bf16x8 b3 = *(const bf16x8*)&lb3[(wn * 32 + nn * 16 + lr) * LDT + kg * 8];
#pragma unroll
            for (int m = 0; m < 4; ++m) {
                acc1[m][nn] = __builtin_amdgcn_mfma_f32_16x16x32_bf16(a[m], b1, acc1[m][nn], 0, 0, 0);
                acc3[m][nn] = __builtin_amdgcn_mfma_f32_16x16x32_bf16(a[m], b3, acc3[m][nn], 0, 0, 0);
            }
        }
    };

    LOADU(A, 0);           // K-step 0
    WRITEU(A, 0);
    LOADU(B, BK);          // K-step 1 — in flight across iter 0

    for (int k = 0; k < NKU - 2; k += 2) {
        __syncthreads();                       // buf0 (K-step k) ready
        LOADU(A, (k + 2) * BK);                // issue K-step k+2 ...
        __builtin_amdgcn_sched_barrier(0);     // ... and pin it here (no sinking)
        mfma_step(0);
        WRITEU(B, 1);                          // K-step k+1 (loaded ~1 iter ago)
        __syncthreads();                       // buf1 (K-step k+1) ready
        LOADU(B, (k + 3) * BK);                // issue K-step k+3
        __builtin_amdgcn_sched_barrier(0);
        mfma_step(1);
        WRITEU(A, 0);                          // K-step k+2
    }
    // epilogue: K-steps NKU-2 (buf0, already written) and NKU-1 (in rB)
    __syncthreads();
    mfma_step(0);
    WRITEU(B, 1);
    __syncthreads();
    mfma_step(1);
#undef LOADU
#undef WRITEU

    const size_t arow0 = (size_t)aofs[e] + (size_t)tt * 128;
#pragma unroll
    for (int m = 0; m < 4; ++m)
#pragma unroll
        for (int nn = 0; nn < 2; ++nn)
#pragma unroll
            for (int r = 0; r < 4; ++r) {
                int row_local = wm * 64 + m * 16 + kg * 4 + r;
                int col = wn * 32 + nn * 16 + lr;
                float h1 = acc1[m][nn][r], h3 = acc3[m][nn][r];
                float av = (h1 / (1.f + __expf(-h1))) * h3 * wt[row_local];
                act[(arow0 + row_local) * F_DIM + (size_t)ft * 64 + col] = f2b(av);
            }
}

// ---------------- down: out[t] += act_row @ W2^T  (fp32 atomics, 4 adds/elem) ----------------
// tile: 128 tokens x 64 H-cols, K split 2x1024, BK=32, 2-deep reg pipeline (pinned).
// (256,2): r8's (256,3) cap made the allocator sink the staging loads
// (VGPR=48 -> pipeline dead, 79 us). Match up's proven recipe.
__global__ __launch_bounds__(256, 2) void down_kernel(
    const float* __restrict__ w2, const ushort* __restrict__ act,
    const int* __restrict__ cnt, const int* __restrict__ aofs,
    const int* __restrict__ tlist, float* __restrict__ out)
{
    const int ht = blockIdx.x;            // 0..15 (64-col tiles of H)
    const int tt = blockIdx.y;            // 0..7  (128-token tiles)
    const int e  = blockIdx.z >> 1;       // 0..7
    const int ks = blockIdx.z & 1;        // K chunk 0..1
    const int n = cnt[e];
    if (tt * 128 >= n) return;

    __shared__ int tok[128];
    __shared__ __align__(16) ushort lds_a[2][128 * LDT];
    __shared__ __align__(16) ushort lds_b[2][64 * LDT];

    const int tid = threadIdx.x;
    if (tid < 128) {
        int slot = tt * 128 + tid;
        tok[tid] = (slot < n) ? tlist[e * T_TOK + slot] : -1;
    }
    __syncthreads();

    const int arow = tid >> 1, aseg = tid & 1;   // A: 128 rows x 2 segs, 32B/thread
    const int brow = tid >> 2, bpart = tid & 3;  // B: 64 rows x 4 segs, 8 fp32/thread
    const ushort* asrc = act + ((size_t)aofs[e] + (size_t)tt * 128 + arow) * F_DIM + ks * KCH + aseg * 16;
    const float*  bsrc = w2 + ((size_t)e * H_DIM + (size_t)ht * 64 + brow) * F_DIM + ks * KCH + bpart * 8;

    uint4 arA0, arA1, arB0, arB1;
    float4 brA0, brA1, brB0, brB1;

#define LOADD(S, k0) { const uint4* s_ = (const uint4*)(asrc + (k0)); \
        ar##S##0 = s_[0]; ar##S##1 = s_[1]; \
        const float4* p_ = (const float4*)(bsrc + (k0)); \
        br##S##0 = p_[0]; br##S##1 = p_[1]; }

#define WRITED(S, buf) { uint4* da_ = (uint4*)&lds_a[buf][arow * LDT + aseg * 16]; \
        da_[0] = ar##S##0; da_[1] = ar##S##1; \
        uint4 pk_; PKW(pk_, br##S##0, br##S##1); \
        *(uint4*)&lds_b[buf][brow * LDT + bpart * 8] = pk_; }

    const int l = tid & 63, w = tid >> 6;
    const int wm = w >> 1, wn = w & 1;           // wave tile: 64 rows x 32 cols
    const int lr = l & 15, kg = l >> 4;

    f32x4 acc[4][2];
#pragma unroll
    for (int m = 0; m < 4; ++m)
#pragma unroll
        for (int nn = 0; nn < 2; ++nn) acc[m][nn] = (f32x4){0.f, 0.f, 0.f, 0.f};

    auto mfma_step = [&](int buf) {
        const ushort* la = lds_a[buf];
        const ushort* lb = lds_b[buf];
        bf16x8 a[4];
#pragma unroll
        for (int m = 0; m < 4; ++m)
            a[m] = *(const bf16x8*)&la[(wm * 64 + m * 16 + lr) * LDT + kg * 8];
#pragma unroll
        for (int nn = 0; nn < 2; ++nn) {
            bf16x8 b = *(const bf16x8*)&lb[(wn * 32 + nn * 16 + lr) * LDT + kg * 8];
#pragma unroll
            for (int m = 0; m < 4; ++m)
                acc[m][nn] = __builtin_amdgcn_mfma_f32_16x16x32_bf16(a[m], b, acc[m][nn], 0, 0, 0);
        }
    };

    LOADD(A, 0);
    WRITED(A, 0);
    LOADD(B, BK);

    for (int k = 0; k < NKD - 2; k += 2) {
        __syncthreads();
        LOADD(A, (k + 2) * BK);
        __builtin_amdgcn_sched_barrier(0);
        mfma_step(0);
        WRITED(B, 1);
        __syncthreads();
        LOADD(B, (k + 3) * BK);
        __builtin_amdgcn_sched_barrier(0);
        mfma_step(1);
        WRITED(A, 0);
    }
    __syncthreads();
    mfma_step(0);
    WRITED(B, 1);
    __syncthreads();
    mfma_step(1);
#undef LOADD
#undef WRITED

#pragma unroll
    for (int m = 0; m < 4; ++m)
#pragma unroll
        for (int nn = 0; nn < 2; ++nn)
#pragma unroll
            for (int r = 0; r < 4; ++r) {
                int row_local = wm * 64 + m * 16 + kg * 4 + r;
                int tkn = tok[row_local];
                if (tkn >= 0) {
                    int col = ht * 64 + wn * 32 + nn * 16 + lr;
                    atomicAdd(&out[(size_t)tkn * H_DIM + col], acc[m][nn][r]);
                }
            }
}

extern "C" void kernel_launch(void* const* d_in, const int* in_sizes, int n_in,
                              void* d_out, int out_size, void* d_ws, size_t ws_size,
                              hipStream_t stream) {
    const float* x  = (const float*)d_in[0];
    const float* gw = (const float*)d_in[1];
    const float* w1 = (const float*)d_in[2];
    const float* w2 = (const float*)d_in[3];
    const float* w3 = (const float*)d_in[4];
    float* out = (float*)d_out;
    float* logits = out + (size_t)T_TOK * H_DIM;

    char* ws = (char*)d_ws;
    int*    cnt   = (int*)(ws + 0);
    int*    aofs  = (int*)(ws + 128);
    int*    tlist = (int*)(ws + 4096);
    float*  wlist = (float*)(ws + 4096 + 32768);
    ushort* xb    = (ushort*)(ws + 131072);
    ushort* act   = (ushort*)(ws + (4u << 20));

    hipMemsetAsync(cnt, 0, NE * sizeof(int), stream);
    hipMemsetAsync(out, 0, (size_t)T_TOK * H_DIM * sizeof(float), stream);

    router_kernel<<<dim3(T_TOK), dim3(64), 0, stream>>>(x, gw, logits, xb, cnt, tlist, wlist);
    prefix_kernel<<<dim3(1), dim3(1), 0, stream>>>(cnt, aofs);
    up_kernel<<<dim3(F_DIM / 64, 8, NE), dim3(256), 0, stream>>>(w1, w3, xb, cnt, aofs, tlist, wlist, act);
    down_kernel<<<dim3(H_DIM / 64, 8, NE * KSPLIT), dim3(256), 0, stream>>>(w2, act, cnt, aofs, tlist, out);
}

// Round 11
// 130.686 us; speedup vs baseline: 1.0537x; 1.0537x over previous
//
#include <hip/hip_runtime.h>
#include <hip/hip_bf16.h>
#include <cstdint>

#define T_TOK 1024
#define H_DIM 1024
#define F_DIM 2048
#define NE 8
#define BK 32
#define LDT 40  // padded LDS row stride in bf16 elements (80 B; banks spread, <=2-way)
#define NKU (H_DIM / BK)   // 32
#define KSPLIT 2
#define KCH (F_DIM / KSPLIT)  // 1024 per down block
#define NKD (KCH / BK)     // 32

typedef __attribute__((ext_vector_type(8))) __bf16 bf16x8;
typedef __attribute__((ext_vector_type(4))) float f32x4;

__device__ __forceinline__ ushort f2b(float f) {
    union { float f; uint32_t u; } v; v.f = f;
    uint32_t r = v.u + 0x7FFFu + ((v.u >> 16) & 1u);  // RNE
    return (ushort)(r >> 16);
}
// packed f32x2 -> bf16x2 via compiler pattern (emits v_cvt_pk_bf16_f32)
__device__ __forceinline__ uint32_t pkcvt(float a, float b) {
    __hip_bfloat162 h = __float22bfloat162_rn(float2{a, b});
    union { __hip_bfloat162 h; uint32_t u; } c; c.h = h; return c.u;
}

// ---------------- router: logits (fp32, exact output), top-2, bucket, x->bf16 ----------------
__global__ __launch_bounds__(64) void router_kernel(
    const float* __restrict__ x, const float* __restrict__ gw,
    float* __restrict__ logits_out, ushort* __restrict__ xb,
    int* __restrict__ cnt, int* __restrict__ tlist, float* __restrict__ wlist)
{
    const int t = blockIdx.x;
    const int l = threadIdx.x;
    const float* xr = x + (size_t)t * H_DIM;
    float4 xv[4];
#pragma unroll
    for (int j = 0; j < 4; ++j) xv[j] = ((const float4*)xr)[l * 4 + j];

    {   // bf16 copy of x row (lane covers 16 contiguous elements)
        uint4 p0, p1;
        p0.x = pkcvt(xv[0].x, xv[0].y);
        p0.y = pkcvt(xv[0].z, xv[0].w);
        p0.z = pkcvt(xv[1].x, xv[1].y);
        p0.w = pkcvt(xv[1].z, xv[1].w);
        p1.x = pkcvt(xv[2].x, xv[2].y);
        p1.y = pkcvt(xv[2].z, xv[2].w);
        p1.z = pkcvt(xv[3].x, xv[3].y);
        p1.w = pkcvt(xv[3].z, xv[3].w);
        uint4* dst = (uint4*)(xb + (size_t)t * H_DIM + l * 16);
        dst[0] = p0; dst[1] = p1;
    }

    float lg[NE];
#pragma unroll
    for (int e = 0; e < NE; ++e) {
        const float* g = gw + (size_t)e * H_DIM;
        float s = 0.f;
#pragma unroll
        for (int j = 0; j < 4; ++j) {
            float4 gv = ((const float4*)g)[l * 4 + j];
            s += xv[j].x * gv.x + xv[j].y * gv.y + xv[j].z * gv.z + xv[j].w * gv.w;
        }
#pragma unroll
        for (int off = 32; off > 0; off >>= 1) s += __shfl_xor(s, off);
        lg[e] = s;
    }
    if (l < NE) logits_out[t * NE + l] = lg[l];

    if (l == 0) {
        int e0 = 0; float m0 = lg[0];
        for (int e = 1; e < NE; ++e) if (lg[e] > m0) { m0 = lg[e]; e0 = e; }
        int e1 = (e0 == 0) ? 1 : 0; float m1 = lg[e1];
        for (int e = 0; e < NE; ++e) if (e != e0 && lg[e] > m1) { m1 = lg[e]; e1 = e; }
        float p1 = __expf(m1 - m0);
        float w0 = 1.f / (1.f + p1);
        float w1v = p1 * w0;
        int p = atomicAdd(&cnt[e0], 1);
        tlist[e0 * T_TOK + p] = t; wlist[e0 * T_TOK + p] = w0;
        p = atomicAdd(&cnt[e1], 1);
        tlist[e1 * T_TOK + p] = t; wlist[e1 * T_TOK + p] = w1v;
    }
}

// ---------------- prefix: 128-aligned packed offsets for act ----------------
__global__ void prefix_kernel(const int* __restrict__ cnt, int* __restrict__ aofs) {
    if (threadIdx.x == 0 && blockIdx.x == 0) {
        int o = 0;
        for (int e = 0; e < NE; ++e) { aofs[e] = o; o += ((cnt[e] + 127) >> 7) << 7; }
    }
}

// packed-convert write macro (plain named locals only — rule #20)
#define PKW(d, s0, s1) { d.x = pkcvt(s0.x, s0.y); d.y = pkcvt(s0.z, s0.w); \
                         d.z = pkcvt(s1.x, s1.y); d.w = pkcvt(s1.z, s1.w); }

// ---------------- up: act = silu(X W1^T) * (X W3^T) * route_w ----------------
// tile: 128 tokens x 64 F-cols, BK=32, 2-deep reg pipeline over 2 LDS buffers.
// PINNED-ILP MODE (r8-measured ~45us): peel + sched_barrier(0) after load-issue,
// (256,2) so staging can live across the MFMA cluster.
__global__ __launch_bounds__(256, 2) void up_kernel(
    const float* __restrict__ w1, const float* __restrict__ w3,
    const ushort* __restrict__ xb,
    const int* __restrict__ cnt, const int* __restrict__ aofs,
    const int* __restrict__ tlist, const float* __restrict__ wlist,
    ushort* __restrict__ act)
{
    const int e = blockIdx.z, tt = blockIdx.y, ft = blockIdx.x;  // ft 0..31
    const int n = cnt[e];
    if (tt * 128 >= n) return;

    __shared__ int tok[128];
    __shared__ float wt[128];
    __shared__ __align__(16) ushort lds_a[2][128 * LDT];
    __shared__ __align__(16) ushort lds_b1[2][64 * LDT];
    __shared__ __align__(16) ushort lds_b3[2][64 * LDT];

    const int tid = threadIdx.x;
    if (tid < 128) {
        int slot = tt * 128 + tid;
        bool v = slot < n;
        tok[tid] = v ? tlist[e * T_TOK + slot] : 0;
        wt[tid]  = v ? wlist[e * T_TOK + slot] : 0.f;
    }
    __syncthreads();

    const int arow = tid >> 1, aseg = tid & 1;   // A: 128 rows x 2 segs, 32B/thread
    const int brow = tid >> 2, bpart = tid & 3;  // B: 64 rows x 4 segs, 8 fp32/thread
    const ushort* asrc = xb + (size_t)tok[arow] * H_DIM + aseg * 16;
    const float* b1src = w1 + ((size_t)e * F_DIM + (size_t)ft * 64 + brow) * H_DIM + bpart * 8;
    const float* b3src = w3 + ((size_t)e * F_DIM + (size_t)ft * 64 + brow) * H_DIM + bpart * 8;

    uint4 arA0, arA1, arB0, arB1;
    float4 b1A0, b1A1, b1B0, b1B1;
    float4 b3A0, b3A1, b3B0, b3B1;

#define LOADU(S, k0) { const uint4* s_ = (const uint4*)(asrc + (k0)); \
        ar##S##0 = s_[0]; ar##S##1 = s_[1]; \
        const float4* p1_ = (const float4*)(b1src + (k0)); \
        b1##S##0 = p1_[0]; b1##S##1 = p1_[1]; \
        const float4* p3_ = (const float4*)(b3src + (k0)); \
        b3##S##0 = p3_[0]; b3##S##1 = p3_[1]; }

#define WRITEU(S, buf) { uint4* da_ = (uint4*)&lds_a[buf][arow * LDT + aseg * 16]; \
        da_[0] = ar##S##0; da_[1] = ar##S##1; \
        uint4 pk_; PKW(pk_, b1##S##0, b1##S##1); \
        *(uint4*)&lds_b1[buf][brow * LDT + bpart * 8] = pk_; \
        PKW(pk_, b3##S##0, b3##S##1); \
        *(uint4*)&lds_b3[buf][brow * LDT + bpart * 8] = pk_; }

    const int l = tid & 63, w = tid >> 6;
    const int wm = w >> 1, wn = w & 1;           // wave tile: 64 rows x 32 cols
    const int lr = l & 15, kg = l >> 4;

    f32x4 acc1[4][2], acc3[4][2];
#pragma unroll
    for (int m = 0; m < 4; ++m)
#pragma unroll
        for (int nn = 0; nn < 2; ++nn) {
            acc1[m][nn] = (f32x4){0.f, 0.f, 0.f, 0.f};
            acc3[m][nn] = (f32x4){0.f, 0.f, 0.f, 0.f};
        }

    auto mfma_step = [&](int buf) {
        const ushort* la  = lds_a[buf];
        const ushort* lb1 = lds_b1[buf];
        const ushort* lb3 = lds_b3[buf];
        bf16x8 a[4];
#pragma unroll
        for (int m = 0; m < 4; ++m)
            a[m] = *(const bf16x8*)&la[(wm * 64 + m * 16 + lr) * LDT + kg * 8];
#pragma unroll
        for (int nn = 0; nn < 2; ++nn) {
            bf16x8 b1 = *(const bf16x8*)&lb1[(wn * 32 + nn * 16 + lr) * LDT + kg * 8];
            bf16x8 b3 = *(const bf16x8*)&lb3[(wn * 32 + nn * 16 + lr) * LDT + kg * 8];
#pragma unroll
            for (int m = 0; m < 4; ++m) {
                acc1[m][nn] = __builtin_amdgcn_mfma_f32_16x16x32_bf16(a[m], b1, acc1[m][nn], 0, 0, 0);
                acc3[m][nn] = __builtin_amdgcn_mfma_f32_16x16x32_bf16(a[m], b3, acc3[m][nn], 0, 0, 0);
            }
        }
    };

    LOADU(A, 0);           // K-step 0
    WRITEU(A, 0);
    LOADU(B, BK);          // K-step 1 — in flight across iter 0

    for (int k = 0; k < NKU - 2; k += 2) {
        __syncthreads();                       // buf0 (K-step k) ready
        LOADU(A, (k + 2) * BK);                // issue K-step k+2 ...
        __builtin_amdgcn_sched_barrier(0);     // ... and pin it here (no sinking)
        mfma_step(0);
        WRITEU(B, 1);                          // K-step k+1 (loaded ~1 iter ago)
        __syncthreads();                       // buf1 (K-step k+1) ready
        LOADU(B, (k + 3) * BK);                // issue K-step k+3
        __builtin_amdgcn_sched_barrier(0);
        mfma_step(1);
        WRITEU(A, 0);                          // K-step k+2
    }
    // epilogue: K-steps NKU-2 (buf0, already written) and NKU-1 (in rB)
    __syncthreads();
    mfma_step(0);
    WRITEU(B, 1);
    __syncthreads();
    mfma_step(1);
#undef LOADU
#undef WRITEU

    const size_t arow0 = (size_t)aofs[e] + (size_t)tt * 128;
#pragma unroll
    for (int m = 0; m < 4; ++m)
#pragma unroll
        for (int nn = 0; nn < 2; ++nn)
#pragma unroll
            for (int r = 0; r < 4; ++r) {
                int row_local = wm * 64 + m * 16 + kg * 4 + r;
                int col = wn * 32 + nn * 16 + lr;
                float h1 = acc1[m][nn][r], h3 = acc3[m][nn][r];
                float av = (h1 / (1.f + __expf(-h1))) * h3 * wt[row_local];
                act[(arow0 + row_local) * F_DIM + (size_t)ft * 64 + col] = f2b(av);
            }
}

// ---------------- down: out[t] += act_row @ W2^T  (fp32 atomics, 4 adds/elem) ----------------
// tile: 128 tokens x 64 H-cols, K split 2x1024, BK=32.
// TLP MODE (r7-measured ~35us): non-peeled loop, no sched_barrier, (256,3);
// compiler sinks staging (VGPR ~48) -> LDS 31KB + low VGPR = ~5 blocks/CU,
// 20 waves/CU cover latency via occupancy. Do NOT pin this kernel (r8/r9: 79us).
__global__ __launch_bounds__(256, 3) void down_kernel(
    const float* __restrict__ w2, const ushort* __restrict__ act,
    const int* __restrict__ cnt, const int* __restrict__ aofs,
    const int* __restrict__ tlist, float* __restrict__ out)
{
    const int ht = blockIdx.x;            // 0..15 (64-col tiles of H)
    const int tt = blockIdx.y;            // 0..7  (128-token tiles)
    const int e  = blockIdx.z >> 1;       // 0..7
    const int ks = blockIdx.z & 1;        // K chunk 0..1
    const int n = cnt[e];
    if (tt * 128 >= n) return;

    __shared__ int tok[128];
    __shared__ __align__(16) ushort lds_a[2][128 * LDT];
    __shared__ __align__(16) ushort lds_b[2][64 * LDT];

    const int tid = threadIdx.x;
    if (tid < 128) {
        int slot = tt * 128 + tid;
        tok[tid] = (slot < n) ? tlist[e * T_TOK + slot] : -1;
    }
    __syncthreads();

    const int arow = tid >> 1, aseg = tid & 1;   // A: 128 rows x 2 segs, 32B/thread
    const int brow = tid >> 2, bpart = tid & 3;  // B: 64 rows x 4 segs, 8 fp32/thread
    const ushort* asrc = act + ((size_t)aofs[e] + (size_t)tt * 128 + arow) * F_DIM + ks * KCH + aseg * 16;
    const float*  bsrc = w2 + ((size_t)e * H_DIM + (size_t)ht * 64 + brow) * F_DIM + ks * KCH + bpart * 8;

    uint4 arA0, arA1, arB0, arB1;
    float4 brA0, brA1, brB0, brB1;

#define LOADD(S, k0) { const uint4* s_ = (const uint4*)(asrc + (k0)); \
        ar##S##0 = s_[0]; ar##S##1 = s_[1]; \
        const float4* p_ = (const float4*)(bsrc + (k0)); \
        br##S##0 = p_[0]; br##S##1 = p_[1]; }

#define WRITED(S, buf) { uint4* da_ = (uint4*)&lds_a[buf][arow * LDT + aseg * 16]; \
        da_[0] = ar##S##0; da_[1] = ar##S##1; \
        uint4 pk_; PKW(pk_, br##S##0, br##S##1); \
        *(uint4*)&lds_b[buf][brow * LDT + bpart * 8] = pk_; }

    const int l = tid & 63, w = tid >> 6;
    const int wm = w >> 1, wn = w & 1;           // wave tile: 64 rows x 32 cols
    const int lr = l & 15, kg = l >> 4;

    f32x4 acc[4][2];
#pragma unroll
    for (int m = 0; m < 4; ++m)
#pragma unroll
        for (int nn = 0; nn < 2; ++nn) acc[m][nn] = (f32x4){0.f, 0.f, 0.f, 0.f};

    auto mfma_step = [&](int buf) {
        const ushort* la = lds_a[buf];
        const ushort* lb = lds_b[buf];
        bf16x8 a[4];
#pragma unroll
        for (int m = 0; m < 4; ++m)
            a[m] = *(const bf16x8*)&la[(wm * 64 + m * 16 + lr) * LDT + kg * 8];
#pragma unroll
        for (int nn = 0; nn < 2; ++nn) {
            bf16x8 b = *(const bf16x8*)&lb[(wn * 32 + nn * 16 + lr) * LDT + kg * 8];
#pragma unroll
            for (int m = 0; m < 4; ++m)
                acc[m][nn] = __builtin_amdgcn_mfma_f32_16x16x32_bf16(a[m], b, acc[m][nn], 0, 0, 0);
        }
    };

    LOADD(A, 0);
    WRITED(A, 0);
    LOADD(B, BK);

    for (int k = 0; k < NKD; k += 2) {
        __syncthreads();
        if (k + 2 < NKD) LOADD(A, (k + 2) * BK);
        mfma_step(0);
        WRITED(B, 1);
        __syncthreads();
        if (k + 3 < NKD) LOADD(B, (k + 3) * BK);
        mfma_step(1);
        if (k + 2 < NKD) WRITED(A, 0);
    }
#undef LOADD
#undef WRITED

#pragma unroll
    for (int m = 0; m < 4; ++m)
#pragma unroll
        for (int nn = 0; nn < 2; ++nn)
#pragma unroll
            for (int r = 0; r < 4; ++r) {
                int row_local = wm * 64 + m * 16 + kg * 4 + r;
                int tkn = tok[row_local];
                if (tkn >= 0) {
                    int col = ht * 64 + wn * 32 + nn * 16 + lr;
                    atomicAdd(&out[(size_t)tkn * H_DIM + col], acc[m][nn][r]);
                }
            }
}

extern "C" void kernel_launch(void* const* d_in, const int* in_sizes, int n_in,
                              void* d_out, int out_size, void* d_ws, size_t ws_size,
                              hipStream_t stream) {
    const float* x  = (const float*)d_in[0];
    const float* gw = (const float*)d_in[1];
    const float* w1 = (const float*)d_in[2];
    const float* w2 = (const float*)d_in[3];
    const float* w3 = (const float*)d_in[4];
    float* out = (float*)d_out;
    float* logits = out + (size_t)T_TOK * H_DIM;

    char* ws = (char*)d_ws;
    int*    cnt   = (int*)(ws + 0);
    int*    aofs  = (int*)(ws + 128);
    int*    tlist = (int*)(ws + 4096);
    float*  wlist = (float*)(ws + 4096 + 32768);
    ushort* xb    = (ushort*)(ws + 131072);
    ushort* act   = (ushort*)(ws + (4u << 20));

    hipMemsetAsync(cnt, 0, NE * sizeof(int), stream);
    hipMemsetAsync(out, 0, (size_t)T_TOK * H_DIM * sizeof(float), stream);

    router_kernel<<<dim3(T_TOK), dim3(64), 0, stream>>>(x, gw, logits, xb, cnt, tlist, wlist);
    prefix_kernel<<<dim3(1), dim3(1), 0, stream>>>(cnt, aofs);
    up_kernel<<<dim3(F_DIM / 64, 8, NE), dim3(256), 0, stream>>>(w1, w3, xb, cnt, aofs, tlist, wlist, act);
    down_kernel<<<dim3(H_DIM / 64, 8, NE * KSPLIT), dim3(256), 0, stream>>>(w2, act, cnt, aofs, tlist, out);
}